// Round 10
// baseline (213.541 us; speedup 1.0000x reference)
//
#include <hip/hip_runtime.h>
#include <hip/hip_bf16.h>
#include <math.h>

#define S_LEN 2048
#define DMODEL 2048
#define NH 16
#define NKVH 4
#define HDIM 128
#define WINDOW 1024

typedef __bf16 bf16;
typedef __bf16 bf16x8 __attribute__((ext_vector_type(8)));
typedef float floatx4 __attribute__((ext_vector_type(4)));

static __device__ __forceinline__ bf16x8 load_bf8(const bf16* p) {
    return *reinterpret_cast<const bf16x8*>(p);
}

// async 16B global->LDS (wave-uniform LDS base + lane*16)
static __device__ __forceinline__ void async16(const bf16* g, bf16* l) {
    __builtin_amdgcn_global_load_lds(
        (const __attribute__((address_space(1))) void*)g,
        (__attribute__((address_space(3))) void*)l, 16, 0, 0);
}

// ---------------- fp32 -> bf16 conversion of x and all weights ----------------
__global__ __launch_bounds__(256) void convert_kernel(
    const float* __restrict__ x, const float* __restrict__ wq,
    const float* __restrict__ wk, const float* __restrict__ wv,
    const float* __restrict__ wo,
    bf16* __restrict__ xb, bf16* __restrict__ wqb, bf16* __restrict__ wkb,
    bf16* __restrict__ wvb, bf16* __restrict__ wob) {
    int i = blockIdx.x * blockDim.x + threadIdx.x;  // one float4 per thread
    const float* src; bf16* dst; int off;
    if      (i < 1048576) { src = x;  dst = xb;  off = i; }
    else if (i < 2097152) { src = wq; dst = wqb; off = i - 1048576; }
    else if (i < 2359296) { src = wk; dst = wkb; off = i - 2097152; }
    else if (i < 2621440) { src = wv; dst = wvb; off = i - 2359296; }
    else if (i < 3670016) { src = wo; dst = wob; off = i - 2621440; }
    else return;
    float4 v = reinterpret_cast<const float4*>(src)[off];
    union { bf16 b[4]; ushort4 u; } t;
    t.b[0] = (bf16)v.x; t.b[1] = (bf16)v.y; t.b[2] = (bf16)v.z; t.b[3] = (bf16)v.w;
    reinterpret_cast<ushort4*>(dst)[off] = t.u;
}

// ====== 128x128 tile, BK=64, dbuf GEMM body (32 MFMA/wave per barrier) =======
#define GEMM_BODY(EXTRA_LDS_DECLS)                                             \
    __shared__ __align__(16) bf16 smem[4 * 128 * 64]; /* 64 KB */              \
    EXTRA_LDS_DECLS                                                            \
    int tid = threadIdx.x;                                                     \
    int lane = tid & 63, wid = tid >> 6;                                       \
    int l15 = lane & 15, quad = lane >> 4;                                     \
    int rlocal = lane >> 3;                                                    \
    int scol = ((lane & 7) ^ rlocal) * 8;                                      \
    const bf16* gA = A + (size_t)(m0 + wid * 32 + rlocal) * K + scol;          \
    const bf16* gB = B + (size_t)(n0 + wid * 32 + rlocal) * K + scol;          \
    int ldsOf = (wid * 32) * 64;                                               \
    floatx4 acc[4][4];                                                         \
    _Pragma("unroll") for (int mi = 0; mi < 4; ++mi)                           \
        _Pragma("unroll") for (int ni = 0; ni < 4; ++ni)                       \
            acc[mi][ni] = floatx4{0.f, 0.f, 0.f, 0.f};                         \
    int mb = (wid & 1) * 64, nb = (wid >> 1) * 64;                             \
    _Pragma("unroll") for (int j = 0; j < 4; ++j) {                            \
        async16(gA + (size_t)(j * 8) * K, smem + ldsOf + j * 512);             \
        async16(gB + (size_t)(j * 8) * K, smem + 16384 + ldsOf + j * 512);     \
    }                                                                          \
    int buf = 0;                                                               \
    for (int k0 = 0; k0 < K; k0 += 64) {                                       \
        __syncthreads();                                                       \
        if (k0 + 64 < K) {                                                     \
            int nof = (buf ^ 1) * 8192;                                        \
            _Pragma("unroll") for (int j = 0; j < 4; ++j) {                    \
                async16(gA + (size_t)(j * 8) * K + k0 + 64,                    \
                        smem + nof + ldsOf + j * 512);                         \
                async16(gB + (size_t)(j * 8) * K + k0 + 64,                    \
                        smem + 16384 + nof + ldsOf + j * 512);                 \
            }                                                                  \
        }                                                                      \
        const bf16* sA = smem + buf * 8192;                                    \
        const bf16* sB = smem + 16384 + buf * 8192;                            \
        _Pragma("unroll") for (int kc = 0; kc < 2; ++kc) {                     \
            bf16x8 af[4], bq[4];                                               \
            _Pragma("unroll") for (int i = 0; i < 4; ++i) {                    \
                int ch = ((kc << 2) + quad) ^ (l15 & 7);                       \
                af[i] = load_bf8(sA + (mb + i * 16 + l15) * 64 + ch * 8);      \
                bq[i] = load_bf8(sB + (nb + i * 16 + l15) * 64 + ch * 8);      \
            }                                                                  \
            _Pragma("unroll") for (int mi = 0; mi < 4; ++mi)                   \
                _Pragma("unroll") for (int ni = 0; ni < 4; ++ni)               \
                    acc[mi][ni] = __builtin_amdgcn_mfma_f32_16x16x32_bf16(     \
                        af[mi], bq[ni], acc[mi][ni], 0, 0, 0);                 \
        }                                                                      \
        buf ^= 1;                                                              \
    }

// ===== QKV GEMM + fused clip + RMSNorm + RoPE (N-tile 128 == one head) ======
// grid.x = m (fast-varying) so consecutive blocks share the B tile (L2).
__global__ __launch_bounds__(256) void gemm_qkv_fused(
    const bf16* __restrict__ A, const bf16* __restrict__ B,
    const float* __restrict__ qw, const float* __restrict__ kw,
    bf16* __restrict__ qb, bf16* __restrict__ kb, bf16* __restrict__ vtb) {
    const int K = 2048;
    int m0 = blockIdx.x * 128, n0 = blockIdx.y * 128;
    GEMM_BODY(__shared__ float rowss[128][2];)

    // ---- clip ----
#pragma unroll
    for (int mi = 0; mi < 4; ++mi)
#pragma unroll
        for (int ni = 0; ni < 4; ++ni)
#pragma unroll
            for (int r = 0; r < 4; ++r)
                acc[mi][ni][r] = fminf(fmaxf(acc[mi][ni][r], -8.0f), 8.0f);

    if (n0 >= 2560) {  // V: transpose-store, no norm/rope
#pragma unroll
        for (int mi = 0; mi < 4; ++mi)
#pragma unroll
            for (int ni = 0; ni < 4; ++ni)
#pragma unroll
                for (int r = 0; r < 4; ++r) {
                    int row = m0 + mb + mi * 16 + quad * 4 + r;
                    int n = n0 + nb + ni * 16 + l15;
                    vtb[(size_t)(n - 2560) * 2048 + row] = (bf16)acc[mi][ni][r];
                }
        return;
    }

    __syncthreads();  // done reading staging; safe to reuse smem as xnorm
    bf16 (*xnorm)[128] = (bf16(*)[128])(smem + 16384);  // 32 KB alias

    // ---- per-row sum of squares ----
#pragma unroll
    for (int mi = 0; mi < 4; ++mi)
#pragma unroll
        for (int r = 0; r < 4; ++r) {
            float s = 0.f;
#pragma unroll
            for (int ni = 0; ni < 4; ++ni) s += acc[mi][ni][r] * acc[mi][ni][r];
#pragma unroll
            for (int o = 1; o < 16; o <<= 1) s += __shfl_xor(s, o, 64);
            if (l15 == 0) rowss[mb + mi * 16 + quad * 4 + r][wid >> 1] = s;
        }
    __syncthreads();

    // ---- normalize (fp32), stash for rope pairing ----
    const float* nw = (n0 < 2048) ? qw : kw;
#pragma unroll
    for (int mi = 0; mi < 4; ++mi)
#pragma unroll
        for (int r = 0; r < 4; ++r) {
            int row = mb + mi * 16 + quad * 4 + r;
            float var = (rowss[row][0] + rowss[row][1]) * (1.0f / 128.0f);
            float rinv = rsqrtf(var + 1e-6f);
#pragma unroll
            for (int ni = 0; ni < 4; ++ni) {
                int col = nb + ni * 16 + l15;
                float xn = acc[mi][ni][r] * rinv * nw[col];
                acc[mi][ni][r] = xn;
                xnorm[row][col] = (bf16)xn;
            }
        }
    __syncthreads();

    // ---- RoPE + store ----
    float invf[4];
#pragma unroll
    for (int ni = 0; ni < 4; ++ni) {
        int fi = (nb + ni * 16 + l15) & 63;
        invf[ni] = __expf((float)fi * (-13.122363377404328f / 64.0f));
    }
    bool lowhalf = (nb == 0);  // wave-uniform
#pragma unroll
    for (int mi = 0; mi < 4; ++mi)
#pragma unroll
        for (int r = 0; r < 4; ++r) {
            int row = mb + mi * 16 + quad * 4 + r;
            float pos = (float)(m0 + row);
#pragma unroll
            for (int ni = 0; ni < 4; ++ni) {
                int col = nb + ni * 16 + l15;
                float ang = pos * invf[ni];
                float c = __cosf(ang), sn = __sinf(ang);
                float part = (float)xnorm[row][col ^ 64];
                float rot = lowhalf ? -part : part;
                float o = acc[mi][ni][r] * c + rot * sn;
                int n = n0 + col;
                int s = m0 + row;
                if (n0 < 2048) qb[(size_t)s * 2048 + n] = (bf16)o;
                else           kb[(size_t)s * 512 + (n - 2048)] = (bf16)o;
            }
        }
}

// ---------- out-proj GEMM: 128x128 tile, BK=64, dbuf (fp32 out) -------------
__global__ __launch_bounds__(256) void gemm_out(
    const bf16* __restrict__ A, const bf16* __restrict__ B,
    float* __restrict__ C) {
    const int K = 2048, N = 2048;
    int m0 = blockIdx.x * 128, n0 = blockIdx.y * 128;
    GEMM_BODY()
#pragma unroll
    for (int mi = 0; mi < 4; ++mi)
#pragma unroll
        for (int ni = 0; ni < 4; ++ni)
#pragma unroll
            for (int r = 0; r < 4; ++r) {
                int m = m0 + mb + mi * 16 + quad * 4 + r;
                int n = n0 + nb + ni * 16 + l15;
                C[(size_t)m * N + n] = acc[mi][ni][r];
            }
}

// -------- flash attention: key-split QK / dim-split PV, shared P -------------
// Per iter: wave w reads only its 16-key slice of sK (4 b128), writes exp'd P
// into block-shared sP; barrier; wave w computes dims [32w,32w+32) reading 8
// P-frags + 4 V-frags. LDS reads/wave/iter: 16 (was 34). Fixed-m softmax.
__global__ __launch_bounds__(256) void attn(
    const bf16* __restrict__ qb, const bf16* __restrict__ kb,
    const bf16* __restrict__ vtb, const float* __restrict__ sinks,
    bf16* __restrict__ attb) {
    __shared__ __align__(16) bf16 sK[2][64 * 128];   // 32 KB, swizzled
    __shared__ __align__(16) bf16 sV[2][128 * 64];   // 32 KB, swizzled
    __shared__ __align__(16) bf16 sP[64 * 72];       // 9 KB shared P, padded
    __shared__ float redu[64][4];                    // row-sum partials
    int tid = threadIdx.x;
    int lane = tid & 63, wid = tid >> 6;
    int l15 = lane & 15, quad = lane >> 4;
    int h = blockIdx.y, kh = h >> 2;
    int bq0 = blockIdx.x * 64;

    // Q stationary: all 64 queries of this block, head h. A[m=l15][k=quad*8+j]
    bf16x8 qf[4][4];
#pragma unroll
    for (int mi = 0; mi < 4; ++mi) {
        const bf16* qrow = qb + (size_t)(bq0 + mi * 16 + l15) * 2048 + h * 128 + quad * 8;
#pragma unroll
        for (int kc = 0; kc < 4; ++kc) qf[mi][kc] = load_bf8(qrow + kc * 32);
    }

    floatx4 acc[4][2];  // [mi][df]: 64 q x this wave's 32 dims
#pragma unroll
    for (int mi = 0; mi < 4; ++mi)
#pragma unroll
        for (int df = 0; df < 2; ++df) acc[mi][df] = floatx4{0.f, 0.f, 0.f, 0.f};
    float lp[4][4];     // [mi][r] partial row sums over this wave's keys
#pragma unroll
    for (int mi = 0; mi < 4; ++mi)
#pragma unroll
        for (int r = 0; r < 4; ++r) lp[mi][r] = 0.f;

    // staging (identical swizzles to R9)
    int keyit = wid * 4 + (lane >> 4);
    int gcK = (lane & 15) ^ keyit;
    int dimit = wid * 8 + (lane >> 3);
    int gcV = (lane & 7) ^ ((lane >> 3) & 7);

    int tstart = bq0 - 1024; if (tstart < 0) tstart = 0;
    const bf16* kbase = kb + (size_t)kh * 128;
    const bf16* vbase = vtb + (size_t)kh * 128 * 2048;

#pragma unroll
    for (int r = 0; r < 4; ++r) {
        async16(kbase + (size_t)(tstart + r * 16 + keyit) * 512 + gcK * 8,
                sK[0] + (r * 16 + wid * 4) * 128);
        async16(vbase + (size_t)(r * 32 + dimit) * 2048 + tstart + gcV * 8,
                sV[0] + (r * 32 + wid * 8) * 64);
    }

    int buf = 0;
    for (int t = tstart; t <= bq0; t += 64) {
        __syncthreads();   // tile(buf) ready; sP from last iter fully consumed
        if (t + 64 <= bq0) {
#pragma unroll
            for (int r = 0; r < 4; ++r) {
                async16(kbase + (size_t)(t + 64 + r * 16 + keyit) * 512 + gcK * 8,
                        sK[buf ^ 1] + (r * 16 + wid * 4) * 128);
                async16(vbase + (size_t)(r * 32 + dimit) * 2048 + t + 64 + gcV * 8,
                        sV[buf ^ 1] + (r * 32 + wid * 8) * 64);
            }
        }
        // ---- phase 1: QK^T for this wave's 16 keys ----
        floatx4 S[4];
#pragma unroll
        for (int mi = 0; mi < 4; ++mi) S[mi] = floatx4{0.f, 0.f, 0.f, 0.f};
#pragma unroll
        for (int kc = 0; kc < 4; ++kc) {
            int ch = (kc * 4 + quad) ^ l15;  // row&15 == l15
            bf16x8 kf = load_bf8(sK[buf] + (wid * 16 + l15) * 128 + ch * 8);
#pragma unroll
            for (int mi = 0; mi < 4; ++mi)
                S[mi] = __builtin_amdgcn_mfma_f32_16x16x32_bf16(qf[mi][kc], kf, S[mi], 0, 0, 0);
        }
        int ki = t + wid * 16 + l15;
#pragma unroll
        for (int mi = 0; mi < 4; ++mi)
#pragma unroll
            for (int r = 0; r < 4; ++r) {
                int qi = bq0 + mi * 16 + quad * 4 + r;
                float v = S[mi][r] * 0.08838834764831845f;  // 1/sqrt(128)
                bool ok = (ki <= qi) && (ki > qi - WINDOW);
                float e = ok ? __expf(v) : 0.0f;
                lp[mi][r] += e;
                sP[(mi * 16 + quad * 4 + r) * 72 + wid * 16 + l15] = (bf16)e;
            }
        __syncthreads();   // P complete
        // ---- phase 2: PV for this wave's 32 dims ----
#pragma unroll
        for (int kc = 0; kc < 2; ++kc) {
            bf16x8 pf[4];
#pragma unroll
            for (int mi = 0; mi < 4; ++mi)
                pf[mi] = load_bf8(sP + (mi * 16 + l15) * 72 + kc * 32 + quad * 8);
#pragma unroll
            for (int df = 0; df < 2; ++df) {
                int dim = wid * 32 + df * 16 + l15;
                int ch = (kc * 4 + quad) ^ (l15 & 7);
                bf16x8 vf = load_bf8(sV[buf] + dim * 64 + ch * 8);
#pragma unroll
                for (int mi = 0; mi < 4; ++mi)
                    acc[mi][df] = __builtin_amdgcn_mfma_f32_16x16x32_bf16(pf[mi], vf, acc[mi][df], 0, 0, 0);
            }
        }
        buf ^= 1;
    }

    // reduce lp over the 16-lane key groups, then across waves via LDS
#pragma unroll
    for (int mi = 0; mi < 4; ++mi)
#pragma unroll
        for (int r = 0; r < 4; ++r) {
            float v = lp[mi][r];
#pragma unroll
            for (int o = 1; o < 16; o <<= 1) v += __shfl_xor(v, o, 64);
            if (l15 == 0) redu[mi * 16 + quad * 4 + r][wid] = v;
        }
    __syncthreads();
    float sk = __expf(sinks[h]);
#pragma unroll
    for (int mi = 0; mi < 4; ++mi)
#pragma unroll
        for (int r = 0; r < 4; ++r) {
            int row = mi * 16 + quad * 4 + r;
            float rs = redu[row][0] + redu[row][1] + redu[row][2] + redu[row][3] + sk;
            float inv = 1.0f / rs;
#pragma unroll
            for (int df = 0; df < 2; ++df) {
                int dim = wid * 32 + df * 16 + l15;
                attb[(size_t)(bq0 + row) * 2048 + h * 128 + dim] =
                    (bf16)(acc[mi][df][r] * inv);
            }
        }
}

extern "C" void kernel_launch(void* const* d_in, const int* in_sizes, int n_in,
                              void* d_out, int out_size, void* d_ws, size_t ws_size,
                              hipStream_t stream) {
    const float* x      = (const float*)d_in[0];
    const float* w_q    = (const float*)d_in[1];
    const float* w_k    = (const float*)d_in[2];
    const float* w_v    = (const float*)d_in[3];
    const float* w_out  = (const float*)d_in[4];
    const float* q_norm = (const float*)d_in[5];
    const float* k_norm = (const float*)d_in[6];
    const float* sinks  = (const float*)d_in[7];

    char* ws = (char*)d_ws;
    const size_t MB = 1u << 20;
    bf16* xb   = (bf16*)(ws + 0 * MB);    // 8 MB
    bf16* wqb  = (bf16*)(ws + 8 * MB);    // 8 MB  (wqb/wkb/wvb contiguous)
    bf16* wkb  = (bf16*)(ws + 16 * MB);   // 2 MB  (forms wcomb [3072][2048])
    bf16* wvb  = (bf16*)(ws + 18 * MB);   // 2 MB
    bf16* wob  = (bf16*)(ws + 20 * MB);   // 8 MB
    bf16* qb   = (bf16*)(ws + 28 * MB);   // 8 MB  (post norm+rope)
    bf16* kb   = (bf16*)(ws + 36 * MB);   // 2 MB
    bf16* vtb  = (bf16*)(ws + 38 * MB);   // 2 MB  (V transposed)
    bf16* attb = (bf16*)(ws + 40 * MB);   // 8 MB
    bf16* wcomb = wqb;                    // rows 0..3071 = [w_q; w_k; w_v]
    float* out = (float*)d_out;

    convert_kernel<<<14336, 256, 0, stream>>>(x, w_q, w_k, w_v, w_out,
                                              xb, wqb, wkb, wvb, wob);
    gemm_qkv_fused<<<dim3(16, 24), 256, 0, stream>>>(xb, wcomb, q_norm, k_norm,
                                                     qb, kb, vtb);
    attn<<<dim3(32, 16), 256, 0, stream>>>(qb, kb, vtb, sinks, attb);
    gemm_out<<<dim3(16, 16), 256, 0, stream>>>(attb, wob, out);
}

// Round 11
// 206.001 us; speedup vs baseline: 1.0366x; 1.0366x over previous
//
#include <hip/hip_runtime.h>
#include <hip/hip_bf16.h>
#include <math.h>

#define S_LEN 2048
#define DMODEL 2048
#define NH 16
#define NKVH 4
#define HDIM 128
#define WINDOW 1024

typedef __bf16 bf16;
typedef __bf16 bf16x8 __attribute__((ext_vector_type(8)));
typedef __bf16 bf16x4 __attribute__((ext_vector_type(4)));
typedef float floatx4 __attribute__((ext_vector_type(4)));

static __device__ __forceinline__ bf16x8 load_bf8(const bf16* p) {
    return *reinterpret_cast<const bf16x8*>(p);
}

// async 16B global->LDS (wave-uniform LDS base + lane*16)
static __device__ __forceinline__ void async16(const bf16* g, bf16* l) {
    __builtin_amdgcn_global_load_lds(
        (const __attribute__((address_space(1))) void*)g,
        (__attribute__((address_space(3))) void*)l, 16, 0, 0);
}

// ---------------- fp32 -> bf16 conversion of x and all weights ----------------
__global__ __launch_bounds__(256) void convert_kernel(
    const float* __restrict__ x, const float* __restrict__ wq,
    const float* __restrict__ wk, const float* __restrict__ wv,
    const float* __restrict__ wo,
    bf16* __restrict__ xb, bf16* __restrict__ wqb, bf16* __restrict__ wkb,
    bf16* __restrict__ wvb, bf16* __restrict__ wob) {
    int i = blockIdx.x * blockDim.x + threadIdx.x;  // one float4 per thread
    const float* src; bf16* dst; int off;
    if      (i < 1048576) { src = x;  dst = xb;  off = i; }
    else if (i < 2097152) { src = wq; dst = wqb; off = i - 1048576; }
    else if (i < 2359296) { src = wk; dst = wkb; off = i - 2097152; }
    else if (i < 2621440) { src = wv; dst = wvb; off = i - 2359296; }
    else if (i < 3670016) { src = wo; dst = wob; off = i - 2621440; }
    else return;
    float4 v = reinterpret_cast<const float4*>(src)[off];
    union { bf16 b[4]; ushort4 u; } t;
    t.b[0] = (bf16)v.x; t.b[1] = (bf16)v.y; t.b[2] = (bf16)v.z; t.b[3] = (bf16)v.w;
    reinterpret_cast<ushort4*>(dst)[off] = t.u;
}

// ====== 128x128 tile, BK=64, dbuf GEMM body (32 MFMA/wave per barrier) =======
#define GEMM_BODY(EXTRA_LDS_DECLS)                                             \
    __shared__ __align__(16) bf16 smem[4 * 128 * 64]; /* 64 KB */              \
    EXTRA_LDS_DECLS                                                            \
    int tid = threadIdx.x;                                                     \
    int lane = tid & 63, wid = tid >> 6;                                       \
    int l15 = lane & 15, quad = lane >> 4;                                     \
    int rlocal = lane >> 3;                                                    \
    int scol = ((lane & 7) ^ rlocal) * 8;                                      \
    const bf16* gA = A + (size_t)(m0 + wid * 32 + rlocal) * K + scol;          \
    const bf16* gB = B + (size_t)(n0 + wid * 32 + rlocal) * K + scol;          \
    int ldsOf = (wid * 32) * 64;                                               \
    floatx4 acc[4][4];                                                         \
    _Pragma("unroll") for (int mi = 0; mi < 4; ++mi)                           \
        _Pragma("unroll") for (int ni = 0; ni < 4; ++ni)                       \
            acc[mi][ni] = floatx4{0.f, 0.f, 0.f, 0.f};                         \
    int mb = (wid & 1) * 64, nb = (wid >> 1) * 64;                             \
    _Pragma("unroll") for (int j = 0; j < 4; ++j) {                            \
        async16(gA + (size_t)(j * 8) * K, smem + ldsOf + j * 512);             \
        async16(gB + (size_t)(j * 8) * K, smem + 16384 + ldsOf + j * 512);     \
    }                                                                          \
    int buf = 0;                                                               \
    for (int k0 = 0; k0 < K; k0 += 64) {                                       \
        __syncthreads();                                                       \
        if (k0 + 64 < K) {                                                     \
            int nof = (buf ^ 1) * 8192;                                        \
            _Pragma("unroll") for (int j = 0; j < 4; ++j) {                    \
                async16(gA + (size_t)(j * 8) * K + k0 + 64,                    \
                        smem + nof + ldsOf + j * 512);                         \
                async16(gB + (size_t)(j * 8) * K + k0 + 64,                    \
                        smem + 16384 + nof + ldsOf + j * 512);                 \
            }                                                                  \
        }                                                                      \
        const bf16* sA = smem + buf * 8192;                                    \
        const bf16* sB = smem + 16384 + buf * 8192;                            \
        _Pragma("unroll") for (int kc = 0; kc < 2; ++kc) {                     \
            bf16x8 af[4], bq[4];                                               \
            _Pragma("unroll") for (int i = 0; i < 4; ++i) {                    \
                int ch = ((kc << 2) + quad) ^ (l15 & 7);                       \
                af[i] = load_bf8(sA + (mb + i * 16 + l15) * 64 + ch * 8);      \
                bq[i] = load_bf8(sB + (nb + i * 16 + l15) * 64 + ch * 8);      \
            }                                                                  \
            _Pragma("unroll") for (int mi = 0; mi < 4; ++mi)                   \
                _Pragma("unroll") for (int ni = 0; ni < 4; ++ni)               \
                    acc[mi][ni] = __builtin_amdgcn_mfma_f32_16x16x32_bf16(     \
                        af[mi], bq[ni], acc[mi][ni], 0, 0, 0);                 \
        }                                                                      \
        buf ^= 1;                                                              \
    }

// ===== QKV GEMM + fused clip + RMSNorm + RoPE (N-tile 128 == one head) ======
// grid: x = n-tiles (fast) so consecutive blocks share the A tile (L2) —
// measured: this order fetches 39 MB vs 53 MB for m-fast.
__global__ __launch_bounds__(256) void gemm_qkv_fused(
    const bf16* __restrict__ A, const bf16* __restrict__ B,
    const float* __restrict__ qw, const float* __restrict__ kw,
    bf16* __restrict__ qb, bf16* __restrict__ kb, bf16* __restrict__ vtb) {
    const int K = 2048;
    int m0 = blockIdx.y * 128, n0 = blockIdx.x * 128;
    GEMM_BODY(__shared__ float rowss[128][2];)

    // ---- clip ----
#pragma unroll
    for (int mi = 0; mi < 4; ++mi)
#pragma unroll
        for (int ni = 0; ni < 4; ++ni)
#pragma unroll
            for (int r = 0; r < 4; ++r)
                acc[mi][ni][r] = fminf(fmaxf(acc[mi][ni][r], -8.0f), 8.0f);

    if (n0 >= 2560) {  // V: transpose-store, no norm/rope
#pragma unroll
        for (int mi = 0; mi < 4; ++mi)
#pragma unroll
            for (int ni = 0; ni < 4; ++ni)
#pragma unroll
                for (int r = 0; r < 4; ++r) {
                    int row = m0 + mb + mi * 16 + quad * 4 + r;
                    int n = n0 + nb + ni * 16 + l15;
                    vtb[(size_t)(n - 2560) * 2048 + row] = (bf16)acc[mi][ni][r];
                }
        return;
    }

    __syncthreads();  // done reading staging; safe to reuse smem as xnorm
    bf16 (*xnorm)[128] = (bf16(*)[128])(smem + 16384);  // 32 KB alias

    // ---- per-row sum of squares ----
#pragma unroll
    for (int mi = 0; mi < 4; ++mi)
#pragma unroll
        for (int r = 0; r < 4; ++r) {
            float s = 0.f;
#pragma unroll
            for (int ni = 0; ni < 4; ++ni) s += acc[mi][ni][r] * acc[mi][ni][r];
#pragma unroll
            for (int o = 1; o < 16; o <<= 1) s += __shfl_xor(s, o, 64);
            if (l15 == 0) rowss[mb + mi * 16 + quad * 4 + r][wid >> 1] = s;
        }
    __syncthreads();

    // ---- normalize (fp32), stash for rope pairing ----
    const float* nw = (n0 < 2048) ? qw : kw;
#pragma unroll
    for (int mi = 0; mi < 4; ++mi)
#pragma unroll
        for (int r = 0; r < 4; ++r) {
            int row = mb + mi * 16 + quad * 4 + r;
            float var = (rowss[row][0] + rowss[row][1]) * (1.0f / 128.0f);
            float rinv = rsqrtf(var + 1e-6f);
#pragma unroll
            for (int ni = 0; ni < 4; ++ni) {
                int col = nb + ni * 16 + l15;
                float xn = acc[mi][ni][r] * rinv * nw[col];
                acc[mi][ni][r] = xn;
                xnorm[row][col] = (bf16)xn;
            }
        }
    __syncthreads();

    // ---- RoPE + store ----
    float invf[4];
#pragma unroll
    for (int ni = 0; ni < 4; ++ni) {
        int fi = (nb + ni * 16 + l15) & 63;
        invf[ni] = __expf((float)fi * (-13.122363377404328f / 64.0f));
    }
    bool lowhalf = (nb == 0);  // wave-uniform
#pragma unroll
    for (int mi = 0; mi < 4; ++mi)
#pragma unroll
        for (int r = 0; r < 4; ++r) {
            int row = mb + mi * 16 + quad * 4 + r;
            float pos = (float)(m0 + row);
#pragma unroll
            for (int ni = 0; ni < 4; ++ni) {
                int col = nb + ni * 16 + l15;
                float ang = pos * invf[ni];
                float c = __cosf(ang), sn = __sinf(ang);
                float part = (float)xnorm[row][col ^ 64];
                float rot = lowhalf ? -part : part;
                float o = acc[mi][ni][r] * c + rot * sn;
                int n = n0 + col;
                int s = m0 + row;
                if (n0 < 2048) qb[(size_t)s * 2048 + n] = (bf16)o;
                else           kb[(size_t)s * 512 + (n - 2048)] = (bf16)o;
            }
        }
}

// ---------- out-proj GEMM: 128x128 tile, BK=64, dbuf (fp32 out) -------------
__global__ __launch_bounds__(256) void gemm_out(
    const bf16* __restrict__ A, const bf16* __restrict__ B,
    float* __restrict__ C) {
    const int K = 2048, N = 2048;
    int m0 = blockIdx.y * 128, n0 = blockIdx.x * 128;
    GEMM_BODY()
#pragma unroll
    for (int mi = 0; mi < 4; ++mi)
#pragma unroll
        for (int ni = 0; ni < 4; ++ni)
#pragma unroll
            for (int r = 0; r < 4; ++r) {
                int m = m0 + mb + mi * 16 + quad * 4 + r;
                int n = n0 + nb + ni * 16 + l15;
                C[(size_t)m * N + n] = acc[mi][ni][r];
            }
}

// -------- flash attention: transposed QK (S^T = K*Q^T), key/dim-split --------
// Phase 1: wave w computes S^T for its 16 keys (A=K rows from sK, B=Q regs);
// C-layout then gives each lane 4 CONSECUTIVE KEYS per query -> P written as
// 4x ds_write_b64 (was 16x b16). Phase 2 (dim-split PV) unchanged.
__global__ __launch_bounds__(256) void attn(
    const bf16* __restrict__ qb, const bf16* __restrict__ kb,
    const bf16* __restrict__ vtb, const float* __restrict__ sinks,
    bf16* __restrict__ attb) {
    __shared__ __align__(16) bf16 sK[2][64 * 128];   // 32 KB, swizzled
    __shared__ __align__(16) bf16 sV[2][128 * 64];   // 32 KB, swizzled
    __shared__ __align__(16) bf16 sP[64 * 72];       // 9 KB shared P, padded
    __shared__ float redu[64][4];                    // row-sum partials
    int tid = threadIdx.x;
    int lane = tid & 63, wid = tid >> 6;
    int l15 = lane & 15, quad = lane >> 4;
    int h = blockIdx.y, kh = h >> 2;
    int bq0 = blockIdx.x * 64;

    // Q stationary: all 64 queries of this block, head h. frag[n=l15][k=quad*8+j]
    bf16x8 qf[4][4];
#pragma unroll
    for (int ni = 0; ni < 4; ++ni) {
        const bf16* qrow = qb + (size_t)(bq0 + ni * 16 + l15) * 2048 + h * 128 + quad * 8;
#pragma unroll
        for (int kc = 0; kc < 4; ++kc) qf[ni][kc] = load_bf8(qrow + kc * 32);
    }

    floatx4 acc[4][2];  // [mi][df]: 64 q x this wave's 32 dims
#pragma unroll
    for (int mi = 0; mi < 4; ++mi)
#pragma unroll
        for (int df = 0; df < 2; ++df) acc[mi][df] = floatx4{0.f, 0.f, 0.f, 0.f};
    float lpq[4];       // per-lane partial row sums (keys quad*4..+4 of wave)
#pragma unroll
    for (int ni = 0; ni < 4; ++ni) lpq[ni] = 0.f;

    // staging (XOR chunk swizzles; LDS dest forced = lane*16)
    int keyit = wid * 4 + (lane >> 4);
    int gcK = (lane & 15) ^ keyit;
    int dimit = wid * 8 + (lane >> 3);
    int gcV = (lane & 7) ^ ((lane >> 3) & 7);

    int tstart = bq0 - 1024; if (tstart < 0) tstart = 0;
    const bf16* kbase = kb + (size_t)kh * 128;
    const bf16* vbase = vtb + (size_t)kh * 128 * 2048;

#pragma unroll
    for (int r = 0; r < 4; ++r) {
        async16(kbase + (size_t)(tstart + r * 16 + keyit) * 512 + gcK * 8,
                sK[0] + (r * 16 + wid * 4) * 128);
        async16(vbase + (size_t)(r * 32 + dimit) * 2048 + tstart + gcV * 8,
                sV[0] + (r * 32 + wid * 8) * 64);
    }

    int buf = 0;
    for (int t = tstart; t <= bq0; t += 64) {
        __syncthreads();   // tile(buf) ready; sP from last iter fully consumed
        if (t + 64 <= bq0) {
#pragma unroll
            for (int r = 0; r < 4; ++r) {
                async16(kbase + (size_t)(t + 64 + r * 16 + keyit) * 512 + gcK * 8,
                        sK[buf ^ 1] + (r * 16 + wid * 4) * 128);
                async16(vbase + (size_t)(r * 32 + dimit) * 2048 + t + 64 + gcV * 8,
                        sV[buf ^ 1] + (r * 32 + wid * 8) * 64);
            }
        }
        // ---- phase 1: S^T = K·Q^T for this wave's 16 keys ----
        floatx4 ST[4];
#pragma unroll
        for (int ni = 0; ni < 4; ++ni) ST[ni] = floatx4{0.f, 0.f, 0.f, 0.f};
#pragma unroll
        for (int kc = 0; kc < 4; ++kc) {
            int ch = (kc * 4 + quad) ^ l15;  // row&15 == l15
            bf16x8 kf = load_bf8(sK[buf] + (wid * 16 + l15) * 128 + ch * 8);
#pragma unroll
            for (int ni = 0; ni < 4; ++ni)
                ST[ni] = __builtin_amdgcn_mfma_f32_16x16x32_bf16(kf, qf[ni][kc], ST[ni], 0, 0, 0);
        }
        int kbi = t + wid * 16 + quad * 4;  // this lane's first key
#pragma unroll
        for (int ni = 0; ni < 4; ++ni) {
            int qi = bq0 + ni * 16 + l15;
            bf16x4 pv;
#pragma unroll
            for (int r = 0; r < 4; ++r) {
                int ki = kbi + r;
                float v = ST[ni][r] * 0.08838834764831845f;  // 1/sqrt(128)
                bool ok = (ki <= qi) && (ki > qi - WINDOW);
                float e = ok ? __expf(v) : 0.0f;
                lpq[ni] += e;
                pv[r] = (bf16)e;
            }
            *(bf16x4*)(sP + (ni * 16 + l15) * 72 + wid * 16 + quad * 4) = pv;
        }
        __syncthreads();   // P complete
        // ---- phase 2: PV for this wave's 32 dims ----
#pragma unroll
        for (int kc = 0; kc < 2; ++kc) {
            bf16x8 pf[4];
#pragma unroll
            for (int mi = 0; mi < 4; ++mi)
                pf[mi] = load_bf8(sP + (mi * 16 + l15) * 72 + kc * 32 + quad * 8);
#pragma unroll
            for (int df = 0; df < 2; ++df) {
                int dim = wid * 32 + df * 16 + l15;
                int ch = (kc * 4 + quad) ^ (l15 & 7);
                bf16x8 vf = load_bf8(sV[buf] + dim * 64 + ch * 8);
#pragma unroll
                for (int mi = 0; mi < 4; ++mi)
                    acc[mi][df] = __builtin_amdgcn_mfma_f32_16x16x32_bf16(pf[mi], vf, acc[mi][df], 0, 0, 0);
            }
        }
        buf ^= 1;
    }

    // reduce lpq over the 4 key-subgroups (quad) of this wave, then cross-wave
#pragma unroll
    for (int ni = 0; ni < 4; ++ni) {
        float v = lpq[ni];
        v += __shfl_xor(v, 16, 64);
        v += __shfl_xor(v, 32, 64);
        if (quad == 0) redu[ni * 16 + l15][wid] = v;
    }
    __syncthreads();
    float sk = __expf(sinks[h]);
#pragma unroll
    for (int mi = 0; mi < 4; ++mi)
#pragma unroll
        for (int r = 0; r < 4; ++r) {
            int row = mi * 16 + quad * 4 + r;
            float rs = redu[row][0] + redu[row][1] + redu[row][2] + redu[row][3] + sk;
            float inv = 1.0f / rs;
#pragma unroll
            for (int df = 0; df < 2; ++df) {
                int dim = wid * 32 + df * 16 + l15;
                attb[(size_t)(bq0 + row) * 2048 + h * 128 + dim] =
                    (bf16)(acc[mi][df][r] * inv);
            }
        }
}

extern "C" void kernel_launch(void* const* d_in, const int* in_sizes, int n_in,
                              void* d_out, int out_size, void* d_ws, size_t ws_size,
                              hipStream_t stream) {
    const float* x      = (const float*)d_in[0];
    const float* w_q    = (const float*)d_in[1];
    const float* w_k    = (const float*)d_in[2];
    const float* w_v    = (const float*)d_in[3];
    const float* w_out  = (const float*)d_in[4];
    const float* q_norm = (const float*)d_in[5];
    const float* k_norm = (const float*)d_in[6];
    const float* sinks  = (const float*)d_in[7];

    char* ws = (char*)d_ws;
    const size_t MB = 1u << 20;
    bf16* xb   = (bf16*)(ws + 0 * MB);    // 8 MB
    bf16* wqb  = (bf16*)(ws + 8 * MB);    // 8 MB  (wqb/wkb/wvb contiguous)
    bf16* wkb  = (bf16*)(ws + 16 * MB);   // 2 MB  (forms wcomb [3072][2048])
    bf16* wvb  = (bf16*)(ws + 18 * MB);   // 2 MB
    bf16* wob  = (bf16*)(ws + 20 * MB);   // 8 MB
    bf16* qb   = (bf16*)(ws + 28 * MB);   // 8 MB  (post norm+rope)
    bf16* kb   = (bf16*)(ws + 36 * MB);   // 2 MB
    bf16* vtb  = (bf16*)(ws + 38 * MB);   // 2 MB  (V transposed)
    bf16* attb = (bf16*)(ws + 40 * MB);   // 8 MB
    bf16* wcomb = wqb;                    // rows 0..3071 = [w_q; w_k; w_v]
    float* out = (float*)d_out;

    convert_kernel<<<14336, 256, 0, stream>>>(x, w_q, w_k, w_v, w_out,
                                              xb, wqb, wkb, wvb, wob);
    gemm_qkv_fused<<<dim3(24, 16), 256, 0, stream>>>(xb, wcomb, q_norm, k_norm,
                                                     qb, kb, vtb);
    attn<<<dim3(32, 16), 256, 0, stream>>>(qb, kb, vtb, sinks, attb);
    gemm_out<<<dim3(16, 16), 256, 0, stream>>>(attb, wob, out);
}